// Round 1
// baseline (572.300 us; speedup 1.0000x reference)
//
#include <hip/hip_runtime.h>
#include <hip/hip_bf16.h>

#define CDIM 512
#define NTOK 4096
#define NH 4
#define DH 128
#define NGRP 32
#define EPS 1e-5f

typedef __attribute__((ext_vector_type(8))) short bf16x8;
typedef __attribute__((ext_vector_type(4))) short short4v;
typedef __attribute__((ext_vector_type(4))) float f32x4;

__device__ inline unsigned short f2bf(float f){
  unsigned int u = __float_as_uint(f);
  u = (u + 0x7fffu + ((u >> 16) & 1u)) >> 16;
  return (unsigned short)u;
}

__device__ inline f32x4 mfma_bf16(bf16x8 a, bf16x8 b, f32x4 c){
  asm("v_mfma_f32_16x16x32_bf16 %0, %1, %2, %0" : "+v"(c) : "v"(a), "v"(b));
  return c;
}

// ---------------- weight fp32 -> bf16 ----------------
__global__ __launch_bounds__(256) void k_convert(const float* __restrict__ qkv_w,
                                                 const float* __restrict__ proj_w,
                                                 unsigned short* __restrict__ qw,
                                                 unsigned short* __restrict__ pw){
  int stride = gridDim.x * blockDim.x;
  int i0 = blockIdx.x * blockDim.x + threadIdx.x;
  for (int i = i0; i < 3*CDIM*CDIM; i += stride) qw[i] = f2bf(qkv_w[i]);
  for (int i = i0; i < CDIM*CDIM; i += stride)   pw[i] = f2bf(proj_w[i]);
}

// ---------------- groupnorm stats: one block per group ----------------
__global__ __launch_bounds__(256) void k_gnstats(const float* __restrict__ x,
                                                 float* __restrict__ stats){
  const int g = blockIdx.x, t = threadIdx.x;
  const f32x4* p = (const f32x4*)(x + (size_t)g * (16*NTOK));
  float s = 0.f, ss = 0.f;
  for (int i = t; i < 16*NTOK/4; i += 256){
    f32x4 v = p[i];
    s  += v[0]+v[1]+v[2]+v[3];
    ss += v[0]*v[0]+v[1]*v[1]+v[2]*v[2]+v[3]*v[3];
  }
  for (int off = 32; off > 0; off >>= 1){ s += __shfl_down(s, off); ss += __shfl_down(ss, off); }
  __shared__ float rs[4], rss[4];
  if ((t & 63) == 0){ rs[t>>6] = s; rss[t>>6] = ss; }
  __syncthreads();
  if (t == 0){
    float S  = rs[0]+rs[1]+rs[2]+rs[3];
    float SS = rss[0]+rss[1]+rss[2]+rss[3];
    const float inv = 1.f / (float)(16*NTOK);
    float mu  = S * inv;
    float var = SS * inv - mu*mu;
    stats[g]        = mu;
    stats[NGRP + g] = rsqrtf(var + EPS);
  }
}

// ---------------- GN apply + transpose: x (C,N) fp32 -> h_t (N,C) bf16 ----------------
__global__ __launch_bounds__(256) void k_gnapply(const float* __restrict__ x,
                                                 const float* __restrict__ stats,
                                                 const float* __restrict__ nw,
                                                 const float* __restrict__ nbias,
                                                 unsigned short* __restrict__ h_t){
  __shared__ float tile[64][68];
  const int n0 = blockIdx.x * 64, c0 = blockIdx.y * 64;
  const int t = threadIdx.x;
  {
    const int cl = t >> 2;
    #pragma unroll
    for (int i = 0; i < 4; i++){
      const int f4 = (t & 3) + i*4;
      *(f32x4*)&tile[cl][f4*4] = *(const f32x4*)(x + (size_t)(c0+cl)*NTOK + n0 + f4*4);
    }
  }
  __syncthreads();
  const int nl = t >> 2, cb = (t & 3) * 16;
  unsigned short ov[16] __attribute__((aligned(8)));
  #pragma unroll
  for (int j = 0; j < 16; j++){
    const int c = c0 + cb + j;
    const int grp = c >> 4;
    const float val = (tile[cb+j][nl] - stats[grp]) * stats[NGRP+grp] * nw[c] + nbias[c];
    ov[j] = f2bf(val);
  }
  unsigned short* dst = h_t + (size_t)(n0+nl)*CDIM + c0 + cb;
  #pragma unroll
  for (int j = 0; j < 4; j++) *(short4v*)(dst + j*4) = *(const short4v*)(ov + j*4);
}

// ---------------- GEMM: A (M,K) bf16 row-major, Bt (N,K) bf16 row-major ----------------
// MODE 0: qkv. writes q_t/k_t (h,N,DH) and v (h,DH,N), bias added, bf16 out.
// MODE 1: proj. out = acc + bias + x  (fp32, (C,N)).
template<int MODE>
__global__ __launch_bounds__(256) void k_gemm(const unsigned short* __restrict__ A,
                                              const unsigned short* __restrict__ Bt,
                                              const float* __restrict__ bias,
                                              const float* __restrict__ xres,
                                              unsigned short* __restrict__ q_t,
                                              unsigned short* __restrict__ k_t,
                                              unsigned short* __restrict__ vbuf,
                                              float* __restrict__ out,
                                              int K)
{
  __shared__ unsigned short Asm[128*32];
  __shared__ unsigned short Bsm[128*32];
  const int m0 = blockIdx.y * 128, n0 = blockIdx.x * 128;
  const int t = threadIdx.x;
  const int lane = t & 63, w = t >> 6;
  const int lo = lane & 15, g = lane >> 4;
  const int wr = w >> 1, wc = w & 1;
  f32x4 acc[4][4];
  #pragma unroll
  for (int i=0;i<4;i++)
    #pragma unroll
    for (int j=0;j<4;j++) acc[i][j] = f32x4{0.f,0.f,0.f,0.f};

  const int row = t >> 2, cb8 = (t & 3) * 8;
  for (int k0 = 0; k0 < K; k0 += 32){
    __syncthreads();
    *(bf16x8*)(Asm + row*32 + cb8)      = *(const bf16x8*)(A  + (size_t)(m0+row)*K    + k0 + cb8);
    *(bf16x8*)(Asm + (row+64)*32 + cb8) = *(const bf16x8*)(A  + (size_t)(m0+row+64)*K + k0 + cb8);
    *(bf16x8*)(Bsm + row*32 + cb8)      = *(const bf16x8*)(Bt + (size_t)(n0+row)*K    + k0 + cb8);
    *(bf16x8*)(Bsm + (row+64)*32 + cb8) = *(const bf16x8*)(Bt + (size_t)(n0+row+64)*K + k0 + cb8);
    __syncthreads();
    bf16x8 af[4], bfr[4];
    #pragma unroll
    for (int i=0;i<4;i++) af[i]  = *(const bf16x8*)(Asm + (wr*64 + i*16 + lo)*32 + g*8);
    #pragma unroll
    for (int j=0;j<4;j++) bfr[j] = *(const bf16x8*)(Bsm + (wc*64 + j*16 + lo)*32 + g*8);
    #pragma unroll
    for (int i=0;i<4;i++)
      #pragma unroll
      for (int j=0;j<4;j++)
        acc[i][j] = mfma_bf16(af[i], bfr[j], acc[i][j]);
  }

  if constexpr (MODE == 0){
    const int sQ = m0 >> 9;          // 0=q,1=k,2=v (BM=128 aligned to head/section)
    const int hh = (m0 >> 7) & 3;
    #pragma unroll
    for (int i=0;i<4;i++){
      const int ddb = wr*64 + i*16 + g*4;       // d index base (m0&127==0)
      const int ob  = m0 + ddb;
      float b[4];
      #pragma unroll
      for (int r=0;r<4;r++) b[r] = bias[ob + r];
      #pragma unroll
      for (int j=0;j<4;j++){
        const int n = n0 + wc*64 + j*16 + lo;
        if (sQ < 2){
          unsigned short pk[4] __attribute__((aligned(8)));
          #pragma unroll
          for (int r=0;r<4;r++) pk[r] = f2bf(acc[i][j][r] + b[r]);
          unsigned short* dst = (sQ == 0 ? q_t : k_t) + ((size_t)hh*NTOK + n)*DH + ddb;
          *(short4v*)dst = *(const short4v*)pk;
        } else {
          #pragma unroll
          for (int r=0;r<4;r++)
            vbuf[((size_t)hh*DH + ddb + r)*NTOK + n] = f2bf(acc[i][j][r] + b[r]);
        }
      }
    }
  } else {
    #pragma unroll
    for (int i=0;i<4;i++){
      const int ob = m0 + wr*64 + i*16 + g*4;
      float b[4];
      #pragma unroll
      for (int r=0;r<4;r++) b[r] = bias[ob + r];
      #pragma unroll
      for (int j=0;j<4;j++){
        const int n = n0 + wc*64 + j*16 + lo;
        #pragma unroll
        for (int r=0;r<4;r++){
          size_t idx = (size_t)(ob + r)*NTOK + n;
          out[idx] = acc[i][j][r] + b[r] + xres[idx];
        }
      }
    }
  }
}

// ---------------- flash attention: wave = 16 query rows ----------------
__global__ __launch_bounds__(128) void k_attn(const unsigned short* __restrict__ q_t,
                                              const unsigned short* __restrict__ k_t,
                                              const unsigned short* __restrict__ vbuf,
                                              unsigned short* __restrict__ ao_t){
  const int h = blockIdx.y;
  const int t = threadIdx.x, w = t >> 6, lane = t & 63;
  const int lo = lane & 15, g = lane >> 4;
  const int nb = blockIdx.x * 32 + w * 16;
  __shared__ unsigned short P[2][16][72];   // per-wave, +8 pad -> 144B row stride (16B aligned)
  const float scale = 0.088388347648318447f;   // 1/sqrt(128)
  const float L2E   = 1.4426950408889634f;

  bf16x8 qa[4];
  {
    const unsigned short* qr = q_t + ((size_t)h*NTOK + nb + lo) * DH;
    #pragma unroll
    for (int ks=0;ks<4;ks++) qa[ks] = *(const bf16x8*)(qr + ks*32 + g*8);
  }
  float mrun[4], lrun[4];
  f32x4 oacc[8];
  #pragma unroll
  for (int r=0;r<4;r++){ mrun[r] = -1e30f; lrun[r] = 0.f; }
  #pragma unroll
  for (int d=0;d<8;d++) oacc[d] = f32x4{0.f,0.f,0.f,0.f};

  for (int mt = 0; mt < NTOK/64; mt++){
    const int m0 = mt*64;
    f32x4 s[4];
    #pragma unroll
    for (int ms=0; ms<4; ms++){
      f32x4 a = f32x4{0.f,0.f,0.f,0.f};
      const unsigned short* kr = k_t + ((size_t)h*NTOK + m0 + ms*16 + lo) * DH;
      #pragma unroll
      for (int ks=0; ks<4; ks++)
        a = mfma_bf16(qa[ks], *(const bf16x8*)(kr + ks*32 + g*8), a);
      #pragma unroll
      for (int r=0;r<4;r++) a[r] *= scale;
      s[ms] = a;
    }
    // row-wise online softmax (row = 4g+r, cols spread over 16 lanes)
    float rmax[4];
    #pragma unroll
    for (int r=0;r<4;r++) rmax[r] = fmaxf(fmaxf(s[0][r], s[1][r]), fmaxf(s[2][r], s[3][r]));
    #pragma unroll
    for (int off=1; off<16; off<<=1)
      #pragma unroll
      for (int r=0;r<4;r++) rmax[r] = fmaxf(rmax[r], __shfl_xor(rmax[r], off));
    float alpha[4], rsum[4];
    #pragma unroll
    for (int r=0;r<4;r++){
      float mn = fmaxf(mrun[r], rmax[r]);
      alpha[r] = exp2f((mrun[r] - mn) * L2E);
      mrun[r] = mn;
      rsum[r] = 0.f;
    }
    #pragma unroll
    for (int ms=0; ms<4; ms++)
      #pragma unroll
      for (int r=0;r<4;r++){
        float pv = exp2f((s[ms][r] - mrun[r]) * L2E);
        s[ms][r] = pv;
        rsum[r] += pv;
      }
    #pragma unroll
    for (int off=1; off<16; off<<=1)
      #pragma unroll
      for (int r=0;r<4;r++) rsum[r] += __shfl_xor(rsum[r], off);
    #pragma unroll
    for (int r=0;r<4;r++) lrun[r] = lrun[r]*alpha[r] + rsum[r];
    // P -> LDS (bf16), rescale O accumulator
    #pragma unroll
    for (int ms=0; ms<4; ms++)
      #pragma unroll
      for (int r=0;r<4;r++) P[w][g*4+r][ms*16+lo] = f2bf(s[ms][r]);
    #pragma unroll
    for (int d=0; d<8; d++)
      #pragma unroll
      for (int r=0;r<4;r++) oacc[d][r] *= alpha[r];
    // PV: A = P (rows n, k = m), B = v[d][m] contiguous along m
    #pragma unroll
    for (int kst=0; kst<2; kst++){
      bf16x8 pa = *(const bf16x8*)(&P[w][lo][kst*32 + g*8]);
      const unsigned short* vr = vbuf + (size_t)h*DH*NTOK + m0 + kst*32 + g*8;
      #pragma unroll
      for (int d=0; d<8; d++)
        oacc[d] = mfma_bf16(pa, *(const bf16x8*)(vr + (size_t)(d*16 + lo)*NTOK), oacc[d]);
    }
  }
  #pragma unroll
  for (int d=0; d<8; d++)
    #pragma unroll
    for (int r=0;r<4;r++){
      float val = oacc[d][r] / lrun[r];
      ao_t[(size_t)(nb + g*4 + r)*CDIM + h*DH + d*16 + lo] = f2bf(val);
    }
}

extern "C" void kernel_launch(void* const* d_in, const int* in_sizes, int n_in,
                              void* d_out, int out_size, void* d_ws, size_t ws_size,
                              hipStream_t stream){
  const float* x      = (const float*)d_in[0];
  const float* norm_w = (const float*)d_in[1];
  const float* norm_b = (const float*)d_in[2];
  const float* qkv_w  = (const float*)d_in[3];
  const float* qkv_b  = (const float*)d_in[4];
  const float* proj_w = (const float*)d_in[5];
  const float* proj_b = (const float*)d_in[6];
  float* out = (float*)d_out;

  char* ws = (char*)d_ws;
  unsigned short* qw  = (unsigned short*)(ws);             // 1536x512 bf16
  unsigned short* pw  = (unsigned short*)(ws + 1572864);   // 512x512 bf16
  unsigned short* h_t = (unsigned short*)(ws + 2097152);   // 4096x512 bf16
  unsigned short* q_t = (unsigned short*)(ws + 6291456);   // 4x4096x128 bf16
  unsigned short* k_t = (unsigned short*)(ws + 10485760);  // 4x4096x128 bf16
  unsigned short* vb  = (unsigned short*)(ws + 14680064);  // 4x128x4096 bf16
  unsigned short* ao  = (unsigned short*)(ws + 18874368);  // 4096x512 bf16
  float* stats        = (float*)(ws + 23068672);           // 64 floats

  hipLaunchKernelGGL(k_convert, dim3(1024), dim3(256), 0, stream, qkv_w, proj_w, qw, pw);
  hipLaunchKernelGGL(k_gnstats, dim3(32), dim3(256), 0, stream, x, stats);
  hipLaunchKernelGGL(k_gnapply, dim3(64, 8), dim3(256), 0, stream, x, stats, norm_w, norm_b, h_t);
  hipLaunchKernelGGL((k_gemm<0>), dim3(32, 12), dim3(256), 0, stream,
                     qw, h_t, qkv_b, (const float*)nullptr,
                     q_t, k_t, vb, (float*)nullptr, 512);
  hipLaunchKernelGGL(k_attn, dim3(128, 4), dim3(128), 0, stream, q_t, k_t, vb, ao);
  hipLaunchKernelGGL((k_gemm<1>), dim3(32, 4), dim3(256), 0, stream,
                     pw, ao, proj_b, x,
                     (unsigned short*)nullptr, (unsigned short*)nullptr, (unsigned short*)nullptr, out, 512);
}

// Round 4
// 191.157 us; speedup vs baseline: 2.9939x; 2.9939x over previous
//
#include <hip/hip_runtime.h>
#include <hip/hip_bf16.h>

#define CDIM 512
#define NTOK 4096
#define NH 4
#define DH 128
#define NGRP 32
#define EPS 1e-5f

typedef __attribute__((ext_vector_type(8))) short bf16x8;
typedef __attribute__((ext_vector_type(4))) short short4v;
typedef __attribute__((ext_vector_type(4))) float f32x4;

__device__ inline unsigned short f2bf(float f){
  unsigned int u = __float_as_uint(f);
  u = (u + 0x7fffu + ((u >> 16) & 1u)) >> 16;
  return (unsigned short)u;
}

__device__ inline f32x4 mfma_bf16(bf16x8 a, bf16x8 b, f32x4 c){
  asm("v_mfma_f32_16x16x32_bf16 %0, %1, %2, %0" : "+v"(c) : "v"(a), "v"(b));
  return c;
}

#define GLD16(gsrc, ldst) \
  __builtin_amdgcn_global_load_lds((__attribute__((address_space(1))) const void*)(gsrc), \
                                   (__attribute__((address_space(3))) void*)(ldst), 16, 0, 0)

// ---------------- weight fp32 -> bf16 ----------------
__global__ __launch_bounds__(256) void k_convert(const float* __restrict__ qkv_w,
                                                 const float* __restrict__ proj_w,
                                                 unsigned short* __restrict__ qw,
                                                 unsigned short* __restrict__ pw){
  int stride = gridDim.x * blockDim.x;
  int i0 = blockIdx.x * blockDim.x + threadIdx.x;
  for (int i = i0; i < 3*CDIM*CDIM; i += stride) qw[i] = f2bf(qkv_w[i]);
  for (int i = i0; i < CDIM*CDIM; i += stride)   pw[i] = f2bf(proj_w[i]);
}

// ---------------- groupnorm stats: one block per group ----------------
__global__ __launch_bounds__(256) void k_gnstats(const float* __restrict__ x,
                                                 float* __restrict__ stats){
  const int g = blockIdx.x, t = threadIdx.x;
  const f32x4* p = (const f32x4*)(x + (size_t)g * (16*NTOK));
  float s = 0.f, ss = 0.f;
  for (int i = t; i < 16*NTOK/4; i += 256){
    f32x4 v = p[i];
    s  += v[0]+v[1]+v[2]+v[3];
    ss += v[0]*v[0]+v[1]*v[1]+v[2]*v[2]+v[3]*v[3];
  }
  for (int off = 32; off > 0; off >>= 1){ s += __shfl_down(s, off); ss += __shfl_down(ss, off); }
  __shared__ float rs[4], rss[4];
  if ((t & 63) == 0){ rs[t>>6] = s; rss[t>>6] = ss; }
  __syncthreads();
  if (t == 0){
    float S  = rs[0]+rs[1]+rs[2]+rs[3];
    float SS = rss[0]+rss[1]+rss[2]+rss[3];
    const float inv = 1.f / (float)(16*NTOK);
    float mu  = S * inv;
    float var = SS * inv - mu*mu;
    stats[g]        = mu;
    stats[NGRP + g] = rsqrtf(var + EPS);
  }
}

// ---------------- GN apply + transpose: x (C,N) fp32 -> h_t (N,C) bf16 ----------------
__global__ __launch_bounds__(256) void k_gnapply(const float* __restrict__ x,
                                                 const float* __restrict__ stats,
                                                 const float* __restrict__ nw,
                                                 const float* __restrict__ nbias,
                                                 unsigned short* __restrict__ h_t){
  __shared__ float tile[64][68];
  const int n0 = blockIdx.x * 64, c0 = blockIdx.y * 64;
  const int t = threadIdx.x;
  {
    const int cl = t >> 2;
    #pragma unroll
    for (int i = 0; i < 4; i++){
      const int f4 = (t & 3) + i*4;
      *(f32x4*)&tile[cl][f4*4] = *(const f32x4*)(x + (size_t)(c0+cl)*NTOK + n0 + f4*4);
    }
  }
  __syncthreads();
  const int nl = t >> 2, cb = (t & 3) * 16;
  unsigned short ov[16] __attribute__((aligned(8)));
  #pragma unroll
  for (int j = 0; j < 16; j++){
    const int c = c0 + cb + j;
    const int grp = c >> 4;
    const float val = (tile[cb+j][nl] - stats[grp]) * stats[NGRP+grp] * nw[c] + nbias[c];
    ov[j] = f2bf(val);
  }
  unsigned short* dst = h_t + (size_t)(n0+nl)*CDIM + c0 + cb;
  #pragma unroll
  for (int j = 0; j < 4; j++) *(short4v*)(dst + j*4) = *(const short4v*)(ov + j*4);
}

// ---------------- GEMM: A (M,K) bf16 row-major, Bt (N,K) bf16 row-major ----------------
template<int MODE>
__global__ __launch_bounds__(256) void k_gemm(const unsigned short* __restrict__ A,
                                              const unsigned short* __restrict__ Bt,
                                              const float* __restrict__ bias,
                                              const float* __restrict__ xres,
                                              unsigned short* __restrict__ q_t,
                                              unsigned short* __restrict__ k_t,
                                              unsigned short* __restrict__ vbuf,
                                              float* __restrict__ out,
                                              int K)
{
  __shared__ unsigned short Asm[128*32];
  __shared__ unsigned short Bsm[128*32];
  const int m0 = blockIdx.y * 128, n0 = blockIdx.x * 128;
  const int t = threadIdx.x;
  const int lane = t & 63, w = t >> 6;
  const int lo = lane & 15, g = lane >> 4;
  const int wr = w >> 1, wc = w & 1;
  f32x4 acc[4][4];
  #pragma unroll
  for (int i=0;i<4;i++)
    #pragma unroll
    for (int j=0;j<4;j++) acc[i][j] = f32x4{0.f,0.f,0.f,0.f};

  const int row = t >> 2, cb8 = (t & 3) * 8;
  for (int k0 = 0; k0 < K; k0 += 32){
    __syncthreads();
    *(bf16x8*)(Asm + row*32 + cb8)      = *(const bf16x8*)(A  + (size_t)(m0+row)*K    + k0 + cb8);
    *(bf16x8*)(Asm + (row+64)*32 + cb8) = *(const bf16x8*)(A  + (size_t)(m0+row+64)*K + k0 + cb8);
    *(bf16x8*)(Bsm + row*32 + cb8)      = *(const bf16x8*)(Bt + (size_t)(n0+row)*K    + k0 + cb8);
    *(bf16x8*)(Bsm + (row+64)*32 + cb8) = *(const bf16x8*)(Bt + (size_t)(n0+row+64)*K + k0 + cb8);
    __syncthreads();
    bf16x8 af[4], bfr[4];
    #pragma unroll
    for (int i=0;i<4;i++) af[i]  = *(const bf16x8*)(Asm + (wr*64 + i*16 + lo)*32 + g*8);
    #pragma unroll
    for (int j=0;j<4;j++) bfr[j] = *(const bf16x8*)(Bsm + (wc*64 + j*16 + lo)*32 + g*8);
    #pragma unroll
    for (int i=0;i<4;i++)
      #pragma unroll
      for (int j=0;j<4;j++)
        acc[i][j] = mfma_bf16(af[i], bfr[j], acc[i][j]);
  }

  if constexpr (MODE == 0){
    const int sQ = m0 >> 9;
    const int hh = (m0 >> 7) & 3;
    #pragma unroll
    for (int i=0;i<4;i++){
      const int ddb = wr*64 + i*16 + g*4;
      const int ob  = m0 + ddb;
      float b[4];
      #pragma unroll
      for (int r=0;r<4;r++) b[r] = bias[ob + r];
      #pragma unroll
      for (int j=0;j<4;j++){
        const int n = n0 + wc*64 + j*16 + lo;
        if (sQ < 2){
          unsigned short pk[4] __attribute__((aligned(8)));
          #pragma unroll
          for (int r=0;r<4;r++) pk[r] = f2bf(acc[i][j][r] + b[r]);
          unsigned short* dst = (sQ == 0 ? q_t : k_t) + ((size_t)hh*NTOK + n)*DH + ddb;
          *(short4v*)dst = *(const short4v*)pk;
        } else {
          #pragma unroll
          for (int r=0;r<4;r++)
            vbuf[((size_t)hh*DH + ddb + r)*NTOK + n] = f2bf(acc[i][j][r] + b[r]);
        }
      }
    }
  } else {
    #pragma unroll
    for (int i=0;i<4;i++){
      const int ob = m0 + wr*64 + i*16 + g*4;
      float b[4];
      #pragma unroll
      for (int r=0;r<4;r++) b[r] = bias[ob + r];
      #pragma unroll
      for (int j=0;j<4;j++){
        const int n = n0 + wc*64 + j*16 + lo;
        #pragma unroll
        for (int r=0;r<4;r++){
          size_t idx = (size_t)(ob + r)*NTOK + n;
          out[idx] = acc[i][j][r] + b[r] + xres[idx];
        }
      }
    }
  }
}

// ---------------- flash attention: 4 waves/block, 64 q rows, LDS-staged K/V ----------------
// K tile: [64][128] bf16 (row=kv token), swizzled 16B-chunk: lds[row][c16] = G[row][c16^(row&7)]
// V tile: [128][64] bf16 (row=d),        swizzled:           lds[row][c16] = G[row][c16^(row&7)]
__global__ __launch_bounds__(256) void k_attn(const unsigned short* __restrict__ q_t,
                                              const unsigned short* __restrict__ k_t,
                                              const unsigned short* __restrict__ vbuf,
                                              unsigned short* __restrict__ ao_t){
  const int h = blockIdx.y;
  const int t = threadIdx.x, w = t >> 6, lane = t & 63;
  const int lo = lane & 15, g = lane >> 4;
  const int sw = lo & 7;
  const int nb = blockIdx.x * 64 + w * 16;

  __shared__ __align__(16) unsigned short Ksm[2][64*128];
  __shared__ __align__(16) unsigned short Vsm[2][128*64];
  __shared__ unsigned short P[4][16][72];

  const float scale = 0.088388347648318447f;   // 1/sqrt(128)
  const float L2E   = 1.4426950408889634f;

  const unsigned short* kg = k_t  + (size_t)h*NTOK*DH;
  const unsigned short* vg = vbuf + (size_t)h*DH*NTOK;

  auto stage = [&](int mt, int buf){
    const unsigned short* kgm = kg + (size_t)mt*64*DH;
    const unsigned short* vgm = vg + mt*64;
    #pragma unroll
    for (int rnd = 0; rnd < 4; rnd++){
      const int c = rnd*256 + w*64 + lane;
      const int row = c >> 4, col = c & 15;
      GLD16(kgm + (size_t)row*DH + (col ^ (row & 7))*8, &Ksm[buf][(rnd*256 + w*64)*8]);
    }
    #pragma unroll
    for (int rnd = 0; rnd < 4; rnd++){
      const int c = rnd*256 + w*64 + lane;
      const int row = c >> 3, col = c & 7;
      GLD16(vgm + (size_t)row*NTOK + (col ^ (row & 7))*8, &Vsm[buf][(rnd*256 + w*64)*8]);
    }
  };

  bf16x8 qa[4];
  {
    const unsigned short* qr = q_t + ((size_t)h*NTOK + nb + lo) * DH;
    #pragma unroll
    for (int ks=0;ks<4;ks++) qa[ks] = *(const bf16x8*)(qr + ks*32 + g*8);
  }
  float mrun[4], lrun[4];
  f32x4 oacc[8];
  #pragma unroll
  for (int r=0;r<4;r++){ mrun[r] = -1e30f; lrun[r] = 0.f; }
  #pragma unroll
  for (int d=0;d<8;d++) oacc[d] = f32x4{0.f,0.f,0.f,0.f};

  stage(0, 0);
  int cur = 0;
  for (int mt = 0; mt < NTOK/64; mt++){
    __syncthreads();                       // drains stage(mt) (vmcnt 0) + all waves sync
    if (mt + 1 < NTOK/64) stage(mt + 1, cur ^ 1);   // overlaps with this tile's compute

    const unsigned short* Ks = Ksm[cur];
    const unsigned short* Vs = Vsm[cur];

    f32x4 s[4];
    #pragma unroll
    for (int ms=0; ms<4; ms++){
      f32x4 a = f32x4{0.f,0.f,0.f,0.f};
      const int rbase = (ms*16 + lo)*128;
      #pragma unroll
      for (int ks=0; ks<4; ks++){
        bf16x8 kf = *(const bf16x8*)(Ks + rbase + (((ks*4 + g) ^ sw) * 8));
        a = mfma_bf16(qa[ks], kf, a);
      }
      #pragma unroll
      for (int r=0;r<4;r++) a[r] *= scale;
      s[ms] = a;
    }
    // row-wise online softmax (row = 4g+r, cols spread over 16 lanes)
    float rmax[4];
    #pragma unroll
    for (int r=0;r<4;r++) rmax[r] = fmaxf(fmaxf(s[0][r], s[1][r]), fmaxf(s[2][r], s[3][r]));
    #pragma unroll
    for (int off=1; off<16; off<<=1)
      #pragma unroll
      for (int r=0;r<4;r++) rmax[r] = fmaxf(rmax[r], __shfl_xor(rmax[r], off));
    float alpha[4], rsum[4];
    #pragma unroll
    for (int r=0;r<4;r++){
      float mn = fmaxf(mrun[r], rmax[r]);
      alpha[r] = exp2f((mrun[r] - mn) * L2E);
      mrun[r] = mn;
      rsum[r] = 0.f;
    }
    #pragma unroll
    for (int ms=0; ms<4; ms++)
      #pragma unroll
      for (int r=0;r<4;r++){
        float pv = exp2f((s[ms][r] - mrun[r]) * L2E);
        s[ms][r] = pv;
        rsum[r] += pv;
      }
    #pragma unroll
    for (int off=1; off<16; off<<=1)
      #pragma unroll
      for (int r=0;r<4;r++) rsum[r] += __shfl_xor(rsum[r], off);
    #pragma unroll
    for (int r=0;r<4;r++) lrun[r] = lrun[r]*alpha[r] + rsum[r];
    // P -> LDS (bf16), rescale O accumulator
    #pragma unroll
    for (int ms=0; ms<4; ms++)
      #pragma unroll
      for (int r=0;r<4;r++) P[w][g*4+r][ms*16+lo] = f2bf(s[ms][r]);
    #pragma unroll
    for (int d=0; d<8; d++)
      #pragma unroll
      for (int r=0;r<4;r++) oacc[d][r] *= alpha[r];
    // PV: A = P (rows n, k = m), B = V tile rows d (swizzled)
    #pragma unroll
    for (int kst=0; kst<2; kst++){
      bf16x8 pa = *(const bf16x8*)(&P[w][lo][kst*32 + g*8]);
      #pragma unroll
      for (int d=0; d<8; d++){
        const int vrow = d*16 + lo;
        bf16x8 vf = *(const bf16x8*)(Vs + vrow*64 + (((kst*4 + g) ^ sw) * 8));
        oacc[d] = mfma_bf16(pa, vf, oacc[d]);
      }
    }
    cur ^= 1;
  }
  #pragma unroll
  for (int d=0; d<8; d++)
    #pragma unroll
    for (int r=0;r<4;r++){
      float val = oacc[d][r] / lrun[r];
      ao_t[(size_t)(nb + g*4 + r)*CDIM + h*DH + d*16 + lo] = f2bf(val);
    }
}

extern "C" void kernel_launch(void* const* d_in, const int* in_sizes, int n_in,
                              void* d_out, int out_size, void* d_ws, size_t ws_size,
                              hipStream_t stream){
  const float* x      = (const float*)d_in[0];
  const float* norm_w = (const float*)d_in[1];
  const float* norm_b = (const float*)d_in[2];
  const float* qkv_w  = (const float*)d_in[3];
  const float* qkv_b  = (const float*)d_in[4];
  const float* proj_w = (const float*)d_in[5];
  const float* proj_b = (const float*)d_in[6];
  float* out = (float*)d_out;

  char* ws = (char*)d_ws;
  unsigned short* qw  = (unsigned short*)(ws);             // 1536x512 bf16
  unsigned short* pw  = (unsigned short*)(ws + 1572864);   // 512x512 bf16
  unsigned short* h_t = (unsigned short*)(ws + 2097152);   // 4096x512 bf16
  unsigned short* q_t = (unsigned short*)(ws + 6291456);   // 4x4096x128 bf16
  unsigned short* k_t = (unsigned short*)(ws + 10485760);  // 4x4096x128 bf16
  unsigned short* vb  = (unsigned short*)(ws + 14680064);  // 4x128x4096 bf16
  unsigned short* ao  = (unsigned short*)(ws + 18874368);  // 4096x512 bf16
  float* stats        = (float*)(ws + 23068672);           // 64 floats

  hipLaunchKernelGGL(k_convert, dim3(1024), dim3(256), 0, stream, qkv_w, proj_w, qw, pw);
  hipLaunchKernelGGL(k_gnstats, dim3(32), dim3(256), 0, stream, x, stats);
  hipLaunchKernelGGL(k_gnapply, dim3(64, 8), dim3(256), 0, stream, x, stats, norm_w, norm_b, h_t);
  hipLaunchKernelGGL((k_gemm<0>), dim3(32, 12), dim3(256), 0, stream,
                     qw, h_t, qkv_b, (const float*)nullptr,
                     q_t, k_t, vb, (float*)nullptr, 512);
  hipLaunchKernelGGL(k_attn, dim3(64, 4), dim3(256), 0, stream, q_t, k_t, vb, ao);
  hipLaunchKernelGGL((k_gemm<1>), dim3(32, 4), dim3(256), 0, stream,
                     pw, ao, proj_b, x,
                     (unsigned short*)nullptr, (unsigned short*)nullptr, (unsigned short*)nullptr, out, 512);
}

// Round 5
// 159.081 us; speedup vs baseline: 3.5975x; 1.2016x over previous
//
#include <hip/hip_runtime.h>
#include <hip/hip_bf16.h>

#define CDIM 512
#define NTOK 4096
#define NH 4
#define DH 128
#define NGRP 32
#define EPS 1e-5f
#define NSPLIT 2
#define TILES_PER_SPLIT (NTOK/64/NSPLIT)

typedef __attribute__((ext_vector_type(8))) short bf16x8;
typedef __attribute__((ext_vector_type(4))) short short4v;
typedef __attribute__((ext_vector_type(4))) float f32x4;

__device__ inline unsigned short f2bf(float f){
  unsigned int u = __float_as_uint(f);
  u = (u + 0x7fffu + ((u >> 16) & 1u)) >> 16;
  return (unsigned short)u;
}

__device__ inline f32x4 mfma_bf16(bf16x8 a, bf16x8 b, f32x4 c){
  asm("v_mfma_f32_16x16x32_bf16 %0, %1, %2, %0" : "+v"(c) : "v"(a), "v"(b));
  return c;
}

#define GLD16(gsrc, ldst) \
  __builtin_amdgcn_global_load_lds((__attribute__((address_space(1))) const void*)(gsrc), \
                                   (__attribute__((address_space(3))) void*)(ldst), 16, 0, 0)

// exp2 scale constant: P = exp(scale*(s-m)) = exp2((s-m)*scale*log2(e))
#define KSC (0.088388347648318447f * 1.4426950408889634f)

// ---------------- weight fp32 -> bf16 ----------------
__global__ __launch_bounds__(256) void k_convert(const float* __restrict__ qkv_w,
                                                 const float* __restrict__ proj_w,
                                                 unsigned short* __restrict__ qw,
                                                 unsigned short* __restrict__ pw){
  int stride = gridDim.x * blockDim.x;
  int i0 = blockIdx.x * blockDim.x + threadIdx.x;
  for (int i = i0; i < 3*CDIM*CDIM; i += stride) qw[i] = f2bf(qkv_w[i]);
  for (int i = i0; i < CDIM*CDIM; i += stride)   pw[i] = f2bf(proj_w[i]);
}

// ---------------- groupnorm stats: one block per group ----------------
__global__ __launch_bounds__(256) void k_gnstats(const float* __restrict__ x,
                                                 float* __restrict__ stats){
  const int g = blockIdx.x, t = threadIdx.x;
  const f32x4* p = (const f32x4*)(x + (size_t)g * (16*NTOK));
  float s = 0.f, ss = 0.f;
  for (int i = t; i < 16*NTOK/4; i += 256){
    f32x4 v = p[i];
    s  += v[0]+v[1]+v[2]+v[3];
    ss += v[0]*v[0]+v[1]*v[1]+v[2]*v[2]+v[3]*v[3];
  }
  for (int off = 32; off > 0; off >>= 1){ s += __shfl_down(s, off); ss += __shfl_down(ss, off); }
  __shared__ float rs[4], rss[4];
  if ((t & 63) == 0){ rs[t>>6] = s; rss[t>>6] = ss; }
  __syncthreads();
  if (t == 0){
    float S  = rs[0]+rs[1]+rs[2]+rs[3];
    float SS = rss[0]+rss[1]+rss[2]+rss[3];
    const float inv = 1.f / (float)(16*NTOK);
    float mu  = S * inv;
    float var = SS * inv - mu*mu;
    stats[g]        = mu;
    stats[NGRP + g] = rsqrtf(var + EPS);
  }
}

// ---------------- GN apply + transpose: x (C,N) fp32 -> h_t (N,C) bf16 ----------------
__global__ __launch_bounds__(256) void k_gnapply(const float* __restrict__ x,
                                                 const float* __restrict__ stats,
                                                 const float* __restrict__ nw,
                                                 const float* __restrict__ nbias,
                                                 unsigned short* __restrict__ h_t){
  __shared__ float tile[64][68];
  const int n0 = blockIdx.x * 64, c0 = blockIdx.y * 64;
  const int t = threadIdx.x;
  {
    const int cl = t >> 2;
    #pragma unroll
    for (int i = 0; i < 4; i++){
      const int f4 = (t & 3) + i*4;
      *(f32x4*)&tile[cl][f4*4] = *(const f32x4*)(x + (size_t)(c0+cl)*NTOK + n0 + f4*4);
    }
  }
  __syncthreads();
  const int nl = t >> 2, cb = (t & 3) * 16;
  unsigned short ov[16] __attribute__((aligned(8)));
  #pragma unroll
  for (int j = 0; j < 16; j++){
    const int c = c0 + cb + j;
    const int grp = c >> 4;
    const float val = (tile[cb+j][nl] - stats[grp]) * stats[NGRP+grp] * nw[c] + nbias[c];
    ov[j] = f2bf(val);
  }
  unsigned short* dst = h_t + (size_t)(n0+nl)*CDIM + c0 + cb;
  #pragma unroll
  for (int j = 0; j < 4; j++) *(short4v*)(dst + j*4) = *(const short4v*)(ov + j*4);
}

// ---------------- GEMM: A (M,K) bf16 row-major, Bt (N,K) bf16 row-major ----------------
template<int MODE>
__global__ __launch_bounds__(256) void k_gemm(const unsigned short* __restrict__ A,
                                              const unsigned short* __restrict__ Bt,
                                              const float* __restrict__ bias,
                                              const float* __restrict__ xres,
                                              unsigned short* __restrict__ q_t,
                                              unsigned short* __restrict__ k_t,
                                              unsigned short* __restrict__ vbuf,
                                              float* __restrict__ out,
                                              int K)
{
  __shared__ unsigned short Asm[128*32];
  __shared__ unsigned short Bsm[128*32];
  const int m0 = blockIdx.y * 128, n0 = blockIdx.x * 128;
  const int t = threadIdx.x;
  const int lane = t & 63, w = t >> 6;
  const int lo = lane & 15, g = lane >> 4;
  const int wr = w >> 1, wc = w & 1;
  f32x4 acc[4][4];
  #pragma unroll
  for (int i=0;i<4;i++)
    #pragma unroll
    for (int j=0;j<4;j++) acc[i][j] = f32x4{0.f,0.f,0.f,0.f};

  const int row = t >> 2, cb8 = (t & 3) * 8;
  for (int k0 = 0; k0 < K; k0 += 32){
    __syncthreads();
    *(bf16x8*)(Asm + row*32 + cb8)      = *(const bf16x8*)(A  + (size_t)(m0+row)*K    + k0 + cb8);
    *(bf16x8*)(Asm + (row+64)*32 + cb8) = *(const bf16x8*)(A  + (size_t)(m0+row+64)*K + k0 + cb8);
    *(bf16x8*)(Bsm + row*32 + cb8)      = *(const bf16x8*)(Bt + (size_t)(n0+row)*K    + k0 + cb8);
    *(bf16x8*)(Bsm + (row+64)*32 + cb8) = *(const bf16x8*)(Bt + (size_t)(n0+row+64)*K + k0 + cb8);
    __syncthreads();
    bf16x8 af[4], bfr[4];
    #pragma unroll
    for (int i=0;i<4;i++) af[i]  = *(const bf16x8*)(Asm + (wr*64 + i*16 + lo)*32 + g*8);
    #pragma unroll
    for (int j=0;j<4;j++) bfr[j] = *(const bf16x8*)(Bsm + (wc*64 + j*16 + lo)*32 + g*8);
    #pragma unroll
    for (int i=0;i<4;i++)
      #pragma unroll
      for (int j=0;j<4;j++)
        acc[i][j] = mfma_bf16(af[i], bfr[j], acc[i][j]);
  }

  if constexpr (MODE == 0){
    const int sQ = m0 >> 9;
    const int hh = (m0 >> 7) & 3;
    #pragma unroll
    for (int i=0;i<4;i++){
      const int ddb = wr*64 + i*16 + g*4;
      const int ob  = m0 + ddb;
      float b[4];
      #pragma unroll
      for (int r=0;r<4;r++) b[r] = bias[ob + r];
      #pragma unroll
      for (int j=0;j<4;j++){
        const int n = n0 + wc*64 + j*16 + lo;
        if (sQ < 2){
          unsigned short pk[4] __attribute__((aligned(8)));
          #pragma unroll
          for (int r=0;r<4;r++) pk[r] = f2bf(acc[i][j][r] + b[r]);
          unsigned short* dst = (sQ == 0 ? q_t : k_t) + ((size_t)hh*NTOK + n)*DH + ddb;
          *(short4v*)dst = *(const short4v*)pk;
        } else {
          #pragma unroll
          for (int r=0;r<4;r++)
            vbuf[((size_t)hh*DH + ddb + r)*NTOK + n] = f2bf(acc[i][j][r] + b[r]);
        }
      }
    }
  } else {
    #pragma unroll
    for (int i=0;i<4;i++){
      const int ob = m0 + wr*64 + i*16 + g*4;
      float b[4];
      #pragma unroll
      for (int r=0;r<4;r++) b[r] = bias[ob + r];
      #pragma unroll
      for (int j=0;j<4;j++){
        const int n = n0 + wc*64 + j*16 + lo;
        #pragma unroll
        for (int r=0;r<4;r++){
          size_t idx = (size_t)(ob + r)*NTOK + n;
          out[idx] = acc[i][j][r] + b[r] + xres[idx];
        }
      }
    }
  }
}

// ---------------- flash attention, kv-split: 4 waves/block, 64 q rows, 32 kv tiles ----------------
// Writes unnormalized O partial (fp32) + (m,l) per row per split; k_merge combines.
__global__ __launch_bounds__(256) void k_attn(const unsigned short* __restrict__ q_t,
                                              const unsigned short* __restrict__ k_t,
                                              const unsigned short* __restrict__ vbuf,
                                              float* __restrict__ opart,
                                              float* __restrict__ mlbuf){
  const int h = blockIdx.y;
  const int qt = blockIdx.x >> 1, split = blockIdx.x & 1;
  const int t = threadIdx.x, w = t >> 6, lane = t & 63;
  const int lo = lane & 15, g = lane >> 4;
  const int sw = lo & 7;
  const int nb = qt * 64 + w * 16;

  __shared__ __align__(16) unsigned short Ksm[2][64*128];
  __shared__ __align__(16) unsigned short Vsm[2][128*64];
  __shared__ unsigned short P[4][16][72];

  const unsigned short* kg = k_t  + (size_t)h*NTOK*DH;
  const unsigned short* vg = vbuf + (size_t)h*DH*NTOK;

  auto stage = [&](int mt, int buf){
    const unsigned short* kgm = kg + (size_t)mt*64*DH;
    const unsigned short* vgm = vg + mt*64;
    #pragma unroll
    for (int rnd = 0; rnd < 4; rnd++){
      const int c = rnd*256 + w*64 + lane;
      const int row = c >> 4, col = c & 15;
      GLD16(kgm + (size_t)row*DH + (col ^ (row & 7))*8, &Ksm[buf][(rnd*256 + w*64)*8]);
    }
    #pragma unroll
    for (int rnd = 0; rnd < 4; rnd++){
      const int c = rnd*256 + w*64 + lane;
      const int row = c >> 3, col = c & 7;
      GLD16(vgm + (size_t)row*NTOK + (col ^ (row & 7))*8, &Vsm[buf][(rnd*256 + w*64)*8]);
    }
  };

  bf16x8 qa[4];
  {
    const unsigned short* qr = q_t + ((size_t)h*NTOK + nb + lo) * DH;
    #pragma unroll
    for (int ks=0;ks<4;ks++) qa[ks] = *(const bf16x8*)(qr + ks*32 + g*8);
  }
  float mrun[4], lrun[4];
  f32x4 oacc[8];
  #pragma unroll
  for (int r=0;r<4;r++){ mrun[r] = -1e30f; lrun[r] = 0.f; }
  #pragma unroll
  for (int d=0;d<8;d++) oacc[d] = f32x4{0.f,0.f,0.f,0.f};

  const int mt0 = split * TILES_PER_SPLIT, mt1 = mt0 + TILES_PER_SPLIT;
  stage(mt0, 0);
  int cur = 0;
  for (int mt = mt0; mt < mt1; mt++){
    __syncthreads();                       // drains stage(mt) (vmcnt 0) + all waves sync
    if (mt + 1 < mt1) stage(mt + 1, cur ^ 1);   // overlaps with this tile's compute

    const unsigned short* Ks = Ksm[cur];
    const unsigned short* Vs = Vsm[cur];

    f32x4 s[4];
    #pragma unroll
    for (int ms=0; ms<4; ms++){
      f32x4 a = f32x4{0.f,0.f,0.f,0.f};
      const int rbase = (ms*16 + lo)*128;
      #pragma unroll
      for (int ks=0; ks<4; ks++){
        bf16x8 kf = *(const bf16x8*)(Ks + rbase + (((ks*4 + g) ^ sw) * 8));
        a = mfma_bf16(qa[ks], kf, a);
      }
      s[ms] = a;     // raw scores; scale folded into exp2 arg
    }
    // row-wise online softmax in raw-score domain (row = 4g+r, cols over 16 lanes)
    float rmax[4];
    #pragma unroll
    for (int r=0;r<4;r++) rmax[r] = fmaxf(fmaxf(s[0][r], s[1][r]), fmaxf(s[2][r], s[3][r]));
    #pragma unroll
    for (int off=1; off<16; off<<=1)
      #pragma unroll
      for (int r=0;r<4;r++) rmax[r] = fmaxf(rmax[r], __shfl_xor(rmax[r], off));
    float alpha[4], rsum[4];
    #pragma unroll
    for (int r=0;r<4;r++){
      float mn = fmaxf(mrun[r], rmax[r]);
      alpha[r] = exp2f((mrun[r] - mn) * KSC);
      mrun[r] = mn;
      rsum[r] = 0.f;
    }
    #pragma unroll
    for (int ms=0; ms<4; ms++)
      #pragma unroll
      for (int r=0;r<4;r++){
        float pv = exp2f((s[ms][r] - mrun[r]) * KSC);
        s[ms][r] = pv;
        rsum[r] += pv;
      }
    #pragma unroll
    for (int off=1; off<16; off<<=1)
      #pragma unroll
      for (int r=0;r<4;r++) rsum[r] += __shfl_xor(rsum[r], off);
    #pragma unroll
    for (int r=0;r<4;r++) lrun[r] = lrun[r]*alpha[r] + rsum[r];
    // P -> LDS (bf16), rescale O accumulator
    #pragma unroll
    for (int ms=0; ms<4; ms++)
      #pragma unroll
      for (int r=0;r<4;r++) P[w][g*4+r][ms*16+lo] = f2bf(s[ms][r]);
    #pragma unroll
    for (int d=0; d<8; d++)
      #pragma unroll
      for (int r=0;r<4;r++) oacc[d][r] *= alpha[r];
    // PV: A = P (rows n, k = m), B = V tile rows d (swizzled)
    #pragma unroll
    for (int kst=0; kst<2; kst++){
      bf16x8 pa = *(const bf16x8*)(&P[w][lo][kst*32 + g*8]);
      #pragma unroll
      for (int d=0; d<8; d++){
        const int vrow = d*16 + lo;
        bf16x8 vf = *(const bf16x8*)(Vs + vrow*64 + (((kst*4 + g) ^ sw) * 8));
        oacc[d] = mfma_bf16(pa, vf, oacc[d]);
      }
    }
    cur ^= 1;
  }
  // write unnormalized partial O (fp32) + m,l
  float* Od = opart + (((size_t)split*NH + h)*NTOK)*DH;
  #pragma unroll
  for (int d=0; d<8; d++)
    #pragma unroll
    for (int r=0;r<4;r++)
      Od[(size_t)(nb + g*4 + r)*DH + d*16 + lo] = oacc[d][r];
  if (lo == 0){
    float* ml = mlbuf + ((size_t)split*NH + h)*NTOK*2;
    #pragma unroll
    for (int r=0;r<4;r++){
      ml[(nb + g*4 + r)*2]     = mrun[r];
      ml[(nb + g*4 + r)*2 + 1] = lrun[r];
    }
  }
}

// ---------------- merge kv-splits -> ao_t (N,C) bf16 ----------------
__global__ __launch_bounds__(256) void k_merge(const float* __restrict__ opart,
                                               const float* __restrict__ mlbuf,
                                               unsigned short* __restrict__ ao_t){
  const int h = blockIdx.y;
  const int n = blockIdx.x*2 + (threadIdx.x >> 7);
  const int d = threadIdx.x & 127;
  const size_t b0 = ((size_t)0*NH + h)*NTOK + n;
  const size_t b1 = ((size_t)1*NH + h)*NTOK + n;
  const float m0 = mlbuf[b0*2], l0 = mlbuf[b0*2+1];
  const float m1 = mlbuf[b1*2], l1 = mlbuf[b1*2+1];
  const float m  = fmaxf(m0, m1);
  const float a0 = exp2f((m0 - m) * KSC);
  const float a1 = exp2f((m1 - m) * KSC);
  const float l  = l0*a0 + l1*a1;
  const float o  = (opart[b0*DH + d]*a0 + opart[b1*DH + d]*a1) / l;
  ao_t[(size_t)n*CDIM + h*DH + d] = f2bf(o);
}

extern "C" void kernel_launch(void* const* d_in, const int* in_sizes, int n_in,
                              void* d_out, int out_size, void* d_ws, size_t ws_size,
                              hipStream_t stream){
  const float* x      = (const float*)d_in[0];
  const float* norm_w = (const float*)d_in[1];
  const float* norm_b = (const float*)d_in[2];
  const float* qkv_w  = (const float*)d_in[3];
  const float* qkv_b  = (const float*)d_in[4];
  const float* proj_w = (const float*)d_in[5];
  const float* proj_b = (const float*)d_in[6];
  float* out = (float*)d_out;

  char* ws = (char*)d_ws;
  unsigned short* qw  = (unsigned short*)(ws);             // 1536x512 bf16
  unsigned short* pw  = (unsigned short*)(ws + 1572864);   // 512x512 bf16
  unsigned short* h_t = (unsigned short*)(ws + 2097152);   // 4096x512 bf16
  unsigned short* q_t = (unsigned short*)(ws + 6291456);   // 4x4096x128 bf16
  unsigned short* k_t = (unsigned short*)(ws + 10485760);  // 4x4096x128 bf16
  unsigned short* vb  = (unsigned short*)(ws + 14680064);  // 4x128x4096 bf16
  unsigned short* ao  = (unsigned short*)(ws + 18874368);  // 4096x512 bf16
  float* stats        = (float*)(ws + 23068672);           // 64 floats
  float* opart        = (float*)(ws + 23072768);           // 2x4x4096x128 f32 = 16 MB
  float* mlbuf        = (float*)(ws + 39849984);           // 2x4x4096x2 f32 = 256 KB
  // end ≈ 40.1 MB of d_ws

  hipLaunchKernelGGL(k_convert, dim3(1024), dim3(256), 0, stream, qkv_w, proj_w, qw, pw);
  hipLaunchKernelGGL(k_gnstats, dim3(32), dim3(256), 0, stream, x, stats);
  hipLaunchKernelGGL(k_gnapply, dim3(64, 8), dim3(256), 0, stream, x, stats, norm_w, norm_b, h_t);
  hipLaunchKernelGGL((k_gemm<0>), dim3(32, 12), dim3(256), 0, stream,
                     qw, h_t, qkv_b, (const float*)nullptr,
                     q_t, k_t, vb, (float*)nullptr, 512);
  hipLaunchKernelGGL(k_attn, dim3(128, 4), dim3(256), 0, stream, q_t, k_t, vb, opart, mlbuf);
  hipLaunchKernelGGL(k_merge, dim3(NTOK/2, NH), dim3(256), 0, stream, opart, mlbuf, ao);
  hipLaunchKernelGGL((k_gemm<1>), dim3(32, 4), dim3(256), 0, stream,
                     pw, ao, proj_b, x,
                     (unsigned short*)nullptr, (unsigned short*)nullptr, (unsigned short*)nullptr, out, 512);
}

// Round 6
// 137.853 us; speedup vs baseline: 4.1515x; 1.1540x over previous
//
#include <hip/hip_runtime.h>
#include <hip/hip_bf16.h>

#define CDIM 512
#define NTOK 4096
#define NH 4
#define DH 128
#define NGRP 32
#define EPS 1e-5f
#define NSPLIT 2
#define TILES_PER_SPLIT (NTOK/64/NSPLIT)

typedef __attribute__((ext_vector_type(8))) short bf16x8;
typedef __attribute__((ext_vector_type(4))) short short4v;
typedef __attribute__((ext_vector_type(4))) float f32x4;

__device__ inline unsigned short f2bf(float f){
  unsigned int u = __float_as_uint(f);
  u = (u + 0x7fffu + ((u >> 16) & 1u)) >> 16;
  return (unsigned short)u;
}

// fast near-RNE pack (2 VALU ops)
__device__ inline unsigned short f2bf_fast(float f){
  return (unsigned short)((__float_as_uint(f) + 0x8000u) >> 16);
}

__device__ inline f32x4 mfma_bf16(bf16x8 a, bf16x8 b, f32x4 c){
  asm("v_mfma_f32_16x16x32_bf16 %0, %1, %2, %0" : "+v"(c) : "v"(a), "v"(b));
  return c;
}

#define GLD16(gsrc, ldst) \
  __builtin_amdgcn_global_load_lds((__attribute__((address_space(1))) const void*)(gsrc), \
                                   (__attribute__((address_space(3))) void*)(ldst), 16, 0, 0)

// exp2 scale constant: P = exp(scale*(s-m)) = exp2((s-m)*scale*log2(e))
#define KSC (0.088388347648318447f * 1.4426950408889634f)
#define THR_RAW 60.0f

// ---------------- weight fp32 -> bf16 ----------------
__global__ __launch_bounds__(256) void k_convert(const float* __restrict__ qkv_w,
                                                 const float* __restrict__ proj_w,
                                                 unsigned short* __restrict__ qw,
                                                 unsigned short* __restrict__ pw){
  int stride = gridDim.x * blockDim.x;
  int i0 = blockIdx.x * blockDim.x + threadIdx.x;
  for (int i = i0; i < 3*CDIM*CDIM; i += stride) qw[i] = f2bf(qkv_w[i]);
  for (int i = i0; i < CDIM*CDIM; i += stride)   pw[i] = f2bf(proj_w[i]);
}

// ---------------- groupnorm stats: one block per group ----------------
__global__ __launch_bounds__(256) void k_gnstats(const float* __restrict__ x,
                                                 float* __restrict__ stats){
  const int g = blockIdx.x, t = threadIdx.x;
  const f32x4* p = (const f32x4*)(x + (size_t)g * (16*NTOK));
  float s = 0.f, ss = 0.f;
  for (int i = t; i < 16*NTOK/4; i += 256){
    f32x4 v = p[i];
    s  += v[0]+v[1]+v[2]+v[3];
    ss += v[0]*v[0]+v[1]*v[1]+v[2]*v[2]+v[3]*v[3];
  }
  for (int off = 32; off > 0; off >>= 1){ s += __shfl_down(s, off); ss += __shfl_down(ss, off); }
  __shared__ float rs[4], rss[4];
  if ((t & 63) == 0){ rs[t>>6] = s; rss[t>>6] = ss; }
  __syncthreads();
  if (t == 0){
    float S  = rs[0]+rs[1]+rs[2]+rs[3];
    float SS = rss[0]+rss[1]+rss[2]+rss[3];
    const float inv = 1.f / (float)(16*NTOK);
    float mu  = S * inv;
    float var = SS * inv - mu*mu;
    stats[g]        = mu;
    stats[NGRP + g] = rsqrtf(var + EPS);
  }
}

// ---------------- GN apply + transpose: x (C,N) fp32 -> h_t (N,C) bf16 ----------------
__global__ __launch_bounds__(256) void k_gnapply(const float* __restrict__ x,
                                                 const float* __restrict__ stats,
                                                 const float* __restrict__ nw,
                                                 const float* __restrict__ nbias,
                                                 unsigned short* __restrict__ h_t){
  __shared__ float tile[64][68];
  const int n0 = blockIdx.x * 64, c0 = blockIdx.y * 64;
  const int t = threadIdx.x;
  {
    const int cl = t >> 2;
    #pragma unroll
    for (int i = 0; i < 4; i++){
      const int f4 = (t & 3) + i*4;
      *(f32x4*)&tile[cl][f4*4] = *(const f32x4*)(x + (size_t)(c0+cl)*NTOK + n0 + f4*4);
    }
  }
  __syncthreads();
  const int nl = t >> 2, cb = (t & 3) * 16;
  unsigned short ov[16] __attribute__((aligned(8)));
  #pragma unroll
  for (int j = 0; j < 16; j++){
    const int c = c0 + cb + j;
    const int grp = c >> 4;
    const float val = (tile[cb+j][nl] - stats[grp]) * stats[NGRP+grp] * nw[c] + nbias[c];
    ov[j] = f2bf(val);
  }
  unsigned short* dst = h_t + (size_t)(n0+nl)*CDIM + c0 + cb;
  #pragma unroll
  for (int j = 0; j < 4; j++) *(short4v*)(dst + j*4) = *(const short4v*)(ov + j*4);
}

// ---------------- GEMM: A (M,K) bf16 row-major, Bt (N,K) bf16 row-major ----------------
template<int MODE>
__global__ __launch_bounds__(256) void k_gemm(const unsigned short* __restrict__ A,
                                              const unsigned short* __restrict__ Bt,
                                              const float* __restrict__ bias,
                                              const float* __restrict__ xres,
                                              unsigned short* __restrict__ q_t,
                                              unsigned short* __restrict__ k_t,
                                              unsigned short* __restrict__ vbuf,
                                              float* __restrict__ out,
                                              int K)
{
  __shared__ unsigned short Asm[128*32];
  __shared__ unsigned short Bsm[128*32];
  const int m0 = blockIdx.y * 128, n0 = blockIdx.x * 128;
  const int t = threadIdx.x;
  const int lane = t & 63, w = t >> 6;
  const int lo = lane & 15, g = lane >> 4;
  const int wr = w >> 1, wc = w & 1;
  f32x4 acc[4][4];
  #pragma unroll
  for (int i=0;i<4;i++)
    #pragma unroll
    for (int j=0;j<4;j++) acc[i][j] = f32x4{0.f,0.f,0.f,0.f};

  const int row = t >> 2, cb8 = (t & 3) * 8;
  for (int k0 = 0; k0 < K; k0 += 32){
    __syncthreads();
    *(bf16x8*)(Asm + row*32 + cb8)      = *(const bf16x8*)(A  + (size_t)(m0+row)*K    + k0 + cb8);
    *(bf16x8*)(Asm + (row+64)*32 + cb8) = *(const bf16x8*)(A  + (size_t)(m0+row+64)*K + k0 + cb8);
    *(bf16x8*)(Bsm + row*32 + cb8)      = *(const bf16x8*)(Bt + (size_t)(n0+row)*K    + k0 + cb8);
    *(bf16x8*)(Bsm + (row+64)*32 + cb8) = *(const bf16x8*)(Bt + (size_t)(n0+row+64)*K + k0 + cb8);
    __syncthreads();
    bf16x8 af[4], bfr[4];
    #pragma unroll
    for (int i=0;i<4;i++) af[i]  = *(const bf16x8*)(Asm + (wr*64 + i*16 + lo)*32 + g*8);
    #pragma unroll
    for (int j=0;j<4;j++) bfr[j] = *(const bf16x8*)(Bsm + (wc*64 + j*16 + lo)*32 + g*8);
    #pragma unroll
    for (int i=0;i<4;i++)
      #pragma unroll
      for (int j=0;j<4;j++)
        acc[i][j] = mfma_bf16(af[i], bfr[j], acc[i][j]);
  }

  if constexpr (MODE == 0){
    const int sQ = m0 >> 9;
    const int hh = (m0 >> 7) & 3;
    #pragma unroll
    for (int i=0;i<4;i++){
      const int ddb = wr*64 + i*16 + g*4;
      const int ob  = m0 + ddb;
      float b[4];
      #pragma unroll
      for (int r=0;r<4;r++) b[r] = bias[ob + r];
      #pragma unroll
      for (int j=0;j<4;j++){
        const int n = n0 + wc*64 + j*16 + lo;
        if (sQ < 2){
          unsigned short pk[4] __attribute__((aligned(8)));
          #pragma unroll
          for (int r=0;r<4;r++) pk[r] = f2bf(acc[i][j][r] + b[r]);
          unsigned short* dst = (sQ == 0 ? q_t : k_t) + ((size_t)hh*NTOK + n)*DH + ddb;
          *(short4v*)dst = *(const short4v*)pk;
        } else {
          #pragma unroll
          for (int r=0;r<4;r++)
            vbuf[((size_t)hh*DH + ddb + r)*NTOK + n] = f2bf(acc[i][j][r] + b[r]);
        }
      }
    }
  } else {
    #pragma unroll
    for (int i=0;i<4;i++){
      const int ob = m0 + wr*64 + i*16 + g*4;
      float b[4];
      #pragma unroll
      for (int r=0;r<4;r++) b[r] = bias[ob + r];
      #pragma unroll
      for (int j=0;j<4;j++){
        const int n = n0 + wc*64 + j*16 + lo;
        #pragma unroll
        for (int r=0;r<4;r++){
          size_t idx = (size_t)(ob + r)*NTOK + n;
          out[idx] = acc[i][j][r] + b[r] + xres[idx];
        }
      }
    }
  }
}

// ---------------- flash attention, kv-split, defer-max + ones-MFMA row sums ----------------
__global__ __launch_bounds__(256) void k_attn(const unsigned short* __restrict__ q_t,
                                              const unsigned short* __restrict__ k_t,
                                              const unsigned short* __restrict__ vbuf,
                                              float* __restrict__ opart,
                                              float* __restrict__ mlbuf){
  const int h = blockIdx.y;
  const int qt = blockIdx.x >> 1, split = blockIdx.x & 1;
  const int t = threadIdx.x, w = t >> 6, lane = t & 63;
  const int lo = lane & 15, g = lane >> 4;
  const int sw = lo & 7;
  const int nb = qt * 64 + w * 16;

  __shared__ __align__(16) unsigned short Ksm[2][64*128];
  __shared__ __align__(16) unsigned short Vsm[2][128*64];
  __shared__ unsigned short P[4][16][72];

  const unsigned short* kg = k_t  + (size_t)h*NTOK*DH;
  const unsigned short* vg = vbuf + (size_t)h*DH*NTOK;

  auto stage = [&](int mt, int buf){
    const unsigned short* kgm = kg + (size_t)mt*64*DH;
    const unsigned short* vgm = vg + mt*64;
    #pragma unroll
    for (int rnd = 0; rnd < 4; rnd++){
      const int c = rnd*256 + w*64 + lane;
      const int row = c >> 4, col = c & 15;
      GLD16(kgm + (size_t)row*DH + (col ^ (row & 7))*8, &Ksm[buf][(rnd*256 + w*64)*8]);
    }
    #pragma unroll
    for (int rnd = 0; rnd < 4; rnd++){
      const int c = rnd*256 + w*64 + lane;
      const int row = c >> 3, col = c & 7;
      GLD16(vgm + (size_t)row*NTOK + (col ^ (row & 7))*8, &Vsm[buf][(rnd*256 + w*64)*8]);
    }
  };

  bf16x8 qa[4];
  {
    const unsigned short* qr = q_t + ((size_t)h*NTOK + nb + lo) * DH;
    #pragma unroll
    for (int ks=0;ks<4;ks++) qa[ks] = *(const bf16x8*)(qr + ks*32 + g*8);
  }
  // ones B-fragment for row-sum MFMA (bf16 1.0 = 0x3F80; layout-proof)
  bf16x8 onesf;
  #pragma unroll
  for (int j=0;j<8;j++) onesf[j] = (short)0x3F80;

  float mrun[4], mk[4];
  f32x4 oacc[8], lacc;
  #pragma unroll
  for (int r=0;r<4;r++){ mrun[r] = -1e30f; mk[r] = -1e30f; }
  #pragma unroll
  for (int d=0;d<8;d++) oacc[d] = f32x4{0.f,0.f,0.f,0.f};
  lacc = f32x4{0.f,0.f,0.f,0.f};

  const int mt0 = split * TILES_PER_SPLIT, mt1 = mt0 + TILES_PER_SPLIT;
  stage(mt0, 0);
  int cur = 0;
  for (int mt = mt0; mt < mt1; mt++){
    __syncthreads();                       // drains stage(mt) (vmcnt 0) + all waves sync
    if (mt + 1 < mt1) stage(mt + 1, cur ^ 1);   // overlaps with this tile's compute

    const unsigned short* Ks = Ksm[cur];
    const unsigned short* Vs = Vsm[cur];

    f32x4 s[4];
    #pragma unroll
    for (int ms=0; ms<4; ms++){
      f32x4 a = f32x4{0.f,0.f,0.f,0.f};
      const int rbase = (ms*16 + lo)*128;
      #pragma unroll
      for (int ks=0; ks<4; ks++){
        bf16x8 kf = *(const bf16x8*)(Ks + rbase + (((ks*4 + g) ^ sw) * 8));
        a = mfma_bf16(qa[ks], kf, a);
      }
      s[ms] = a;     // raw scores; scale folded into exp2 arg
    }
    // defer-max fast/slow path
    float rmax[4];
    #pragma unroll
    for (int r=0;r<4;r++) rmax[r] = fmaxf(fmaxf(s[0][r], s[1][r]), fmaxf(s[2][r], s[3][r]));
    float tmax = fmaxf(fmaxf(rmax[0], rmax[1]), fmaxf(rmax[2], rmax[3]));
    #pragma unroll
    for (int off=1; off<16; off<<=1) tmax = fmaxf(tmax, __shfl_xor(tmax, off));
    const float mmin = fminf(fminf(mrun[0], mrun[1]), fminf(mrun[2], mrun[3]));
    if (!__all(tmax <= mmin + THR_RAW)){
      // slow path: full per-row online-softmax rescale
      #pragma unroll
      for (int off=1; off<16; off<<=1)
        #pragma unroll
        for (int r=0;r<4;r++) rmax[r] = fmaxf(rmax[r], __shfl_xor(rmax[r], off));
      #pragma unroll
      for (int r=0;r<4;r++){
        float mn = fmaxf(mrun[r], rmax[r]);
        float al = exp2f((mrun[r] - mn) * KSC);
        mrun[r] = mn;
        mk[r]   = mn * KSC;
        lacc[r] *= al;
        #pragma unroll
        for (int d=0;d<8;d++) oacc[d][r] *= al;
      }
    }
    // P = exp2(s*KSC - mk[r]) -> LDS (bf16, fast pack)
    #pragma unroll
    for (int ms=0; ms<4; ms++)
      #pragma unroll
      for (int r=0;r<4;r++){
        float pv = exp2f(fmaf(s[ms][r], KSC, -mk[r]));
        P[w][g*4+r][ms*16+lo] = f2bf_fast(pv);
      }
    // PV: A = P (rows n, k = m), B = V tile rows d (swizzled); +ones-MFMA row sum
    #pragma unroll
    for (int kst=0; kst<2; kst++){
      bf16x8 pa = *(const bf16x8*)(&P[w][lo][kst*32 + g*8]);
      lacc = mfma_bf16(pa, onesf, lacc);
      #pragma unroll
      for (int d=0; d<8; d++){
        const int vrow = d*16 + lo;
        bf16x8 vf = *(const bf16x8*)(Vs + vrow*64 + (((kst*4 + g) ^ sw) * 8));
        oacc[d] = mfma_bf16(pa, vf, oacc[d]);
      }
    }
    cur ^= 1;
  }
  // write unnormalized partial O (fp32) + m,l
  float* Od = opart + (((size_t)split*NH + h)*NTOK)*DH;
  #pragma unroll
  for (int d=0; d<8; d++)
    #pragma unroll
    for (int r=0;r<4;r++)
      Od[(size_t)(nb + g*4 + r)*DH + d*16 + lo] = oacc[d][r];
  if (lo == 0){
    float* ml = mlbuf + ((size_t)split*NH + h)*NTOK*2;
    #pragma unroll
    for (int r=0;r<4;r++){
      ml[(nb + g*4 + r)*2]     = mrun[r];
      ml[(nb + g*4 + r)*2 + 1] = lacc[r];
    }
  }
}

// ---------------- merge kv-splits -> ao_t (N,C) bf16 ----------------
__global__ __launch_bounds__(256) void k_merge(const float* __restrict__ opart,
                                               const float* __restrict__ mlbuf,
                                               unsigned short* __restrict__ ao_t){
  const int h = blockIdx.y;
  const int n = blockIdx.x*2 + (threadIdx.x >> 7);
  const int d = threadIdx.x & 127;
  const size_t b0 = ((size_t)0*NH + h)*NTOK + n;
  const size_t b1 = ((size_t)1*NH + h)*NTOK + n;
  const float m0 = mlbuf[b0*2], l0 = mlbuf[b0*2+1];
  const float m1 = mlbuf[b1*2], l1 = mlbuf[b1*2+1];
  const float m  = fmaxf(m0, m1);
  const float a0 = exp2f((m0 - m) * KSC);
  const float a1 = exp2f((m1 - m) * KSC);
  const float l  = l0*a0 + l1*a1;
  const float o  = (opart[b0*DH + d]*a0 + opart[b1*DH + d]*a1) / l;
  ao_t[(size_t)n*CDIM + h*DH + d] = f2bf(o);
}

extern "C" void kernel_launch(void* const* d_in, const int* in_sizes, int n_in,
                              void* d_out, int out_size, void* d_ws, size_t ws_size,
                              hipStream_t stream){
  const float* x      = (const float*)d_in[0];
  const float* norm_w = (const float*)d_in[1];
  const float* norm_b = (const float*)d_in[2];
  const float* qkv_w  = (const float*)d_in[3];
  const float* qkv_b  = (const float*)d_in[4];
  const float* proj_w = (const float*)d_in[5];
  const float* proj_b = (const float*)d_in[6];
  float* out = (float*)d_out;

  char* ws = (char*)d_ws;
  unsigned short* qw  = (unsigned short*)(ws);             // 1536x512 bf16
  unsigned short* pw  = (unsigned short*)(ws + 1572864);   // 512x512 bf16
  unsigned short* h_t = (unsigned short*)(ws + 2097152);   // 4096x512 bf16
  unsigned short* q_t = (unsigned short*)(ws + 6291456);   // 4x4096x128 bf16
  unsigned short* k_t = (unsigned short*)(ws + 10485760);  // 4x4096x128 bf16
  unsigned short* vb  = (unsigned short*)(ws + 14680064);  // 4x128x4096 bf16
  unsigned short* ao  = (unsigned short*)(ws + 18874368);  // 4096x512 bf16
  float* stats        = (float*)(ws + 23068672);           // 64 floats
  float* opart        = (float*)(ws + 23072768);           // 2x4x4096x128 f32 = 16 MB
  float* mlbuf        = (float*)(ws + 39849984);           // 2x4x4096x2 f32 = 256 KB

  hipLaunchKernelGGL(k_convert, dim3(1024), dim3(256), 0, stream, qkv_w, proj_w, qw, pw);
  hipLaunchKernelGGL(k_gnstats, dim3(32), dim3(256), 0, stream, x, stats);
  hipLaunchKernelGGL(k_gnapply, dim3(64, 8), dim3(256), 0, stream, x, stats, norm_w, norm_b, h_t);
  hipLaunchKernelGGL((k_gemm<0>), dim3(32, 12), dim3(256), 0, stream,
                     qw, h_t, qkv_b, (const float*)nullptr,
                     q_t, k_t, vb, (float*)nullptr, 512);
  hipLaunchKernelGGL(k_attn, dim3(128, 4), dim3(256), 0, stream, q_t, k_t, vb, opart, mlbuf);
  hipLaunchKernelGGL(k_merge, dim3(NTOK/2, NH), dim3(256), 0, stream, opart, mlbuf, ao);
  hipLaunchKernelGGL((k_gemm<1>), dim3(32, 4), dim3(256), 0, stream,
                     pw, ao, proj_b, x,
                     (unsigned short*)nullptr, (unsigned short*)nullptr, (unsigned short*)nullptr, out, 512);
}

// Round 7
// 126.555 us; speedup vs baseline: 4.5221x; 1.0893x over previous
//
#include <hip/hip_runtime.h>
#include <hip/hip_bf16.h>

#define CDIM 512
#define NTOK 4096
#define NH 4
#define DH 128
#define NGRP 32
#define EPS 1e-5f
#define NSPLIT 4
#define KVBLK 64
#define TPS (NTOK/KVBLK/NSPLIT)   // 16 tiles per split

typedef __attribute__((ext_vector_type(8))) short bf16x8;
typedef __attribute__((ext_vector_type(4))) short short4v;
typedef __attribute__((ext_vector_type(4))) float f32x4;
typedef __attribute__((ext_vector_type(16))) float f32x16;

__device__ inline unsigned short f2bf(float f){
  unsigned int u = __float_as_uint(f);
  u = (u + 0x7fffu + ((u >> 16) & 1u)) >> 16;
  return (unsigned short)u;
}

// fast near-RNE pack (2 VALU ops)
__device__ inline unsigned short f2bf_fast(float f){
  return (unsigned short)((__float_as_uint(f) + 0x8000u) >> 16);
}

__device__ inline float bf2f(unsigned short u){
  return __uint_as_float(((unsigned int)u) << 16);
}

__device__ inline f32x4 mfma_bf16(bf16x8 a, bf16x8 b, f32x4 c){
  asm("v_mfma_f32_16x16x32_bf16 %0, %1, %2, %0" : "+v"(c) : "v"(a), "v"(b));
  return c;
}

__device__ inline f32x16 mfma32(bf16x8 a, bf16x8 b, f32x16 c){
  asm("v_mfma_f32_32x32x16_bf16 %0, %1, %2, %0" : "+v"(c) : "v"(a), "v"(b));
  return c;
}

#define GLD16(gsrc, ldst) \
  __builtin_amdgcn_global_load_lds((__attribute__((address_space(1))) const void*)(gsrc), \
                                   (__attribute__((address_space(3))) void*)(ldst), 16, 0, 0)

// exp2 scale constant: P = exp(scale*(s-m)) = exp2(s*KSC - m*KSC)
#define KSC (0.088388347648318447f * 1.4426950408889634f)
#define INV_KSC (1.0f / KSC)
#define THR_RAW 60.0f
#define THR_K (THR_RAW * KSC)

// ---------------- weight fp32 -> bf16 ----------------
__global__ __launch_bounds__(256) void k_convert(const float* __restrict__ qkv_w,
                                                 const float* __restrict__ proj_w,
                                                 unsigned short* __restrict__ qw,
                                                 unsigned short* __restrict__ pw){
  int stride = gridDim.x * blockDim.x;
  int i0 = blockIdx.x * blockDim.x + threadIdx.x;
  for (int i = i0; i < 3*CDIM*CDIM; i += stride) qw[i] = f2bf(qkv_w[i]);
  for (int i = i0; i < CDIM*CDIM; i += stride)   pw[i] = f2bf(proj_w[i]);
}

// ---------------- groupnorm stats: one block per group ----------------
__global__ __launch_bounds__(256) void k_gnstats(const float* __restrict__ x,
                                                 float* __restrict__ stats){
  const int g = blockIdx.x, t = threadIdx.x;
  const f32x4* p = (const f32x4*)(x + (size_t)g * (16*NTOK));
  float s = 0.f, ss = 0.f;
  for (int i = t; i < 16*NTOK/4; i += 256){
    f32x4 v = p[i];
    s  += v[0]+v[1]+v[2]+v[3];
    ss += v[0]*v[0]+v[1]*v[1]+v[2]*v[2]+v[3]*v[3];
  }
  for (int off = 32; off > 0; off >>= 1){ s += __shfl_down(s, off); ss += __shfl_down(ss, off); }
  __shared__ float rs[4], rss[4];
  if ((t & 63) == 0){ rs[t>>6] = s; rss[t>>6] = ss; }
  __syncthreads();
  if (t == 0){
    float S  = rs[0]+rs[1]+rs[2]+rs[3];
    float SS = rss[0]+rss[1]+rss[2]+rss[3];
    const float inv = 1.f / (float)(16*NTOK);
    float mu  = S * inv;
    float var = SS * inv - mu*mu;
    stats[g]        = mu;
    stats[NGRP + g] = rsqrtf(var + EPS);
  }
}

// ---------------- GN apply + transpose: x (C,N) fp32 -> h_t (N,C) bf16 ----------------
__global__ __launch_bounds__(256) void k_gnapply(const float* __restrict__ x,
                                                 const float* __restrict__ stats,
                                                 const float* __restrict__ nw,
                                                 const float* __restrict__ nbias,
                                                 unsigned short* __restrict__ h_t){
  __shared__ float tile[64][68];
  const int n0 = blockIdx.x * 64, c0 = blockIdx.y * 64;
  const int t = threadIdx.x;
  {
    const int cl = t >> 2;
    #pragma unroll
    for (int i = 0; i < 4; i++){
      const int f4 = (t & 3) + i*4;
      *(f32x4*)&tile[cl][f4*4] = *(const f32x4*)(x + (size_t)(c0+cl)*NTOK + n0 + f4*4);
    }
  }
  __syncthreads();
  const int nl = t >> 2, cb = (t & 3) * 16;
  unsigned short ov[16] __attribute__((aligned(8)));
  #pragma unroll
  for (int j = 0; j < 16; j++){
    const int c = c0 + cb + j;
    const int grp = c >> 4;
    const float val = (tile[cb+j][nl] - stats[grp]) * stats[NGRP+grp] * nw[c] + nbias[c];
    ov[j] = f2bf(val);
  }
  unsigned short* dst = h_t + (size_t)(n0+nl)*CDIM + c0 + cb;
  #pragma unroll
  for (int j = 0; j < 4; j++) *(short4v*)(dst + j*4) = *(const short4v*)(ov + j*4);
}

// ---------------- GEMM: A (M,K) bf16 row-major, Bt (N,K) bf16 row-major ----------------
template<int MODE>
__global__ __launch_bounds__(256) void k_gemm(const unsigned short* __restrict__ A,
                                              const unsigned short* __restrict__ Bt,
                                              const float* __restrict__ bias,
                                              const float* __restrict__ xres,
                                              unsigned short* __restrict__ q_t,
                                              unsigned short* __restrict__ k_t,
                                              unsigned short* __restrict__ vbuf,
                                              float* __restrict__ out,
                                              int K)
{
  __shared__ unsigned short Asm[128*32];
  __shared__ unsigned short Bsm[128*32];
  const int m0 = blockIdx.y * 128, n0 = blockIdx.x * 128;
  const int t = threadIdx.x;
  const int lane = t & 63, w = t >> 6;
  const int lo = lane & 15, g = lane >> 4;
  const int wr = w >> 1, wc = w & 1;
  f32x4 acc[4][4];
  #pragma unroll
  for (int i=0;i<4;i++)
    #pragma unroll
    for (int j=0;j<4;j++) acc[i][j] = f32x4{0.f,0.f,0.f,0.f};

  const int row = t >> 2, cb8 = (t & 3) * 8;
  for (int k0 = 0; k0 < K; k0 += 32){
    __syncthreads();
    *(bf16x8*)(Asm + row*32 + cb8)      = *(const bf16x8*)(A  + (size_t)(m0+row)*K    + k0 + cb8);
    *(bf16x8*)(Asm + (row+64)*32 + cb8) = *(const bf16x8*)(A  + (size_t)(m0+row+64)*K + k0 + cb8);
    *(bf16x8*)(Bsm + row*32 + cb8)      = *(const bf16x8*)(Bt + (size_t)(n0+row)*K    + k0 + cb8);
    *(bf16x8*)(Bsm + (row+64)*32 + cb8) = *(const bf16x8*)(Bt + (size_t)(n0+row+64)*K + k0 + cb8);
    __syncthreads();
    bf16x8 af[4], bfr[4];
    #pragma unroll
    for (int i=0;i<4;i++) af[i]  = *(const bf16x8*)(Asm + (wr*64 + i*16 + lo)*32 + g*8);
    #pragma unroll
    for (int j=0;j<4;j++) bfr[j] = *(const bf16x8*)(Bsm + (wc*64 + j*16 + lo)*32 + g*8);
    #pragma unroll
    for (int i=0;i<4;i++)
      #pragma unroll
      for (int j=0;j<4;j++)
        acc[i][j] = mfma_bf16(af[i], bfr[j], acc[i][j]);
  }

  if constexpr (MODE == 0){
    const int sQ = m0 >> 9;
    const int hh = (m0 >> 7) & 3;
    #pragma unroll
    for (int i=0;i<4;i++){
      const int ddb = wr*64 + i*16 + g*4;
      const int ob  = m0 + ddb;
      float b[4];
      #pragma unroll
      for (int r=0;r<4;r++) b[r] = bias[ob + r];
      #pragma unroll
      for (int j=0;j<4;j++){
        const int n = n0 + wc*64 + j*16 + lo;
        if (sQ < 2){
          unsigned short pk[4] __attribute__((aligned(8)));
          #pragma unroll
          for (int r=0;r<4;r++) pk[r] = f2bf(acc[i][j][r] + b[r]);
          unsigned short* dst = (sQ == 0 ? q_t : k_t) + ((size_t)hh*NTOK + n)*DH + ddb;
          *(short4v*)dst = *(const short4v*)pk;
        } else {
          #pragma unroll
          for (int r=0;r<4;r++)
            vbuf[((size_t)hh*DH + ddb + r)*NTOK + n] = f2bf(acc[i][j][r] + b[r]);
        }
      }
    }
  } else {
    #pragma unroll
    for (int i=0;i<4;i++){
      const int ob = m0 + wr*64 + i*16 + g*4;
      float b[4];
      #pragma unroll
      for (int r=0;r<4;r++) b[r] = bias[ob + r];
      #pragma unroll
      for (int j=0;j<4;j++){
        const int n = n0 + wc*64 + j*16 + lo;
        #pragma unroll
        for (int r=0;r<4;r++){
          size_t idx = (size_t)(ob + r)*NTOK + n;
          out[idx] = acc[i][j][r] + b[r] + xres[idx];
        }
      }
    }
  }
}

// ---------------- flash attention: 32x32 MFMA, 8 waves x 32q = 256 q/block ----------------
// K tile [64][128] bf16, chunk16 swizzle ^(row&15); V tile [128][64], ^(row&7).
// P per-wave [32][72] (144B stride). kv-split NSPLIT=4, normalized bf16 partials.
__global__ __launch_bounds__(512, 2) void k_attn(const unsigned short* __restrict__ q_t,
                                                 const unsigned short* __restrict__ k_t,
                                                 const unsigned short* __restrict__ vbuf,
                                                 unsigned short* __restrict__ opart,
                                                 float* __restrict__ mlbuf){
  const int h = blockIdx.y;
  const int qt = blockIdx.x >> 2, split = blockIdx.x & 3;
  const int t = threadIdx.x, w = t >> 6, lane = t & 63;
  const int la = lane & 31, hi = lane >> 5;
  const int s15 = la & 15, s7 = la & 7;
  const int nbq = qt * 256 + w * 32;

  __shared__ __align__(16) unsigned short Ksm[2][64*128];
  __shared__ __align__(16) unsigned short Vsm[2][128*64];
  __shared__ __align__(16) unsigned short P[8][32][72];

  const unsigned short* kg = k_t  + (size_t)h*NTOK*DH;
  const unsigned short* vg = vbuf + (size_t)h*DH*NTOK;

  auto stage = [&](int mt, int buf){
    const unsigned short* kgm = kg + (size_t)mt*KVBLK*DH;
    const unsigned short* vgm = vg + mt*KVBLK;
    #pragma unroll
    for (int rnd = 0; rnd < 2; rnd++){       // K: 1024 chunks / 512 threads
      const int c = rnd*512 + t;
      const int row = c >> 4, col = c & 15;
      GLD16(kgm + (size_t)row*DH + ((col ^ (row & 15))*8), &Ksm[buf][c*8]);
    }
    #pragma unroll
    for (int rnd = 0; rnd < 2; rnd++){       // V: 1024 chunks / 512 threads
      const int c = rnd*512 + t;
      const int row = c >> 3, col = c & 7;
      GLD16(vgm + (size_t)row*NTOK + ((col ^ (row & 7))*8), &Vsm[buf][c*8]);
    }
  };

  // Q fragments: row = la (q), k-slice d = ks*16 + hi*8 + j
  bf16x8 qa[8];
  {
    const unsigned short* qr = q_t + ((size_t)h*NTOK + nbq + la)*DH + hi*8;
    #pragma unroll
    for (int ks=0;ks<8;ks++) qa[ks] = *(const bf16x8*)(qr + ks*16);
  }
  bf16x8 onesf;
  #pragma unroll
  for (int j=0;j<8;j++) onesf[j] = (short)0x3F80;

  float mk[16];                 // running max * KSC, per C-row reg
  f32x16 oacc[4], lacc;
  #pragma unroll
  for (int r=0;r<16;r++){ mk[r] = -1e30f; }
  #pragma unroll
  for (int dt=0;dt<4;dt++)
    #pragma unroll
    for (int r=0;r<16;r++) oacc[dt][r] = 0.f;
  #pragma unroll
  for (int r=0;r<16;r++) lacc[r] = 0.f;

  const int mt0 = split * TPS;
  stage(mt0, 0);
  int cur = 0;
  for (int it = 0; it < TPS; it++){
    __syncthreads();                            // drains stage(it) + sync
    if (it + 1 < TPS) stage(mt0 + it + 1, cur ^ 1);

    const unsigned short* Ks = Ksm[cur];
    const unsigned short* Vs = Vsm[cur];

    // QK^T: S[q][kv], two 32-kv n-tiles
    f32x16 s0, s1;
    #pragma unroll
    for (int r=0;r<16;r++){ s0[r] = 0.f; s1[r] = 0.f; }
    #pragma unroll
    for (int ks=0; ks<8; ks++){
      const int kc = ((2*ks + hi) ^ s15) * 8;
      bf16x8 kf0 = *(const bf16x8*)(Ks + la*128 + kc);
      bf16x8 kf1 = *(const bf16x8*)(Ks + (32+la)*128 + kc);
      s0 = mfma32(qa[ks], kf0, s0);
      s1 = mfma32(qa[ks], kf1, s1);
    }
    // defer-max fast/slow path (in mk = m*KSC domain)
    float tmax = s0[0];
    #pragma unroll
    for (int r=1;r<16;r++) tmax = fmaxf(tmax, s0[r]);
    #pragma unroll
    for (int r=0;r<16;r++) tmax = fmaxf(tmax, s1[r]);
    #pragma unroll
    for (int off=1; off<64; off<<=1) tmax = fmaxf(tmax, __shfl_xor(tmax, off));
    float mmink = mk[0];
    #pragma unroll
    for (int r=1;r<16;r++) mmink = fminf(mmink, mk[r]);
    if (!__all(tmax * KSC <= mmink + THR_K)){
      float rmax[16];
      #pragma unroll
      for (int r=0;r<16;r++) rmax[r] = fmaxf(s0[r], s1[r]);
      #pragma unroll
      for (int off=1; off<32; off<<=1)
        #pragma unroll
        for (int r=0;r<16;r++) rmax[r] = fmaxf(rmax[r], __shfl_xor(rmax[r], off));
      #pragma unroll
      for (int r=0;r<16;r++){
        float mold = mk[r] * INV_KSC;
        float mn   = fmaxf(mold, rmax[r]);
        float mnk  = mn * KSC;
        float al   = exp2f(mk[r] - mnk);
        mk[r] = mnk;
        lacc[r] *= al;
        #pragma unroll
        for (int dt=0;dt<4;dt++) oacc[dt][r] *= al;
      }
    }
    // P = exp2(s*KSC - mk) -> per-wave LDS
    unsigned short* Pw = &P[w][0][0];
    #pragma unroll
    for (int r=0;r<16;r++){
      const int q = (r&3) + 8*(r>>2) + 4*hi;
      float p0 = exp2f(fmaf(s0[r], KSC, -mk[r]));
      float p1 = exp2f(fmaf(s1[r], KSC, -mk[r]));
      Pw[q*72 + la]      = f2bf_fast(p0);
      Pw[q*72 + 32 + la] = f2bf_fast(p1);
    }
    // PV + ones row-sum
    bf16x8 pa[4];
    #pragma unroll
    for (int kst=0;kst<4;kst++)
      pa[kst] = *(const bf16x8*)(&P[w][la][kst*16 + hi*8]);
    #pragma unroll
    for (int kst=0;kst<4;kst++) lacc = mfma32(pa[kst], onesf, lacc);
    #pragma unroll
    for (int dt=0; dt<4; dt++){
      const int vbase = (dt*32 + la)*64;
      #pragma unroll
      for (int kst=0;kst<4;kst++){
        const int vc = ((2*kst + hi) ^ s7) * 8;
        bf16x8 vf = *(const bf16x8*)(Vs + vbase + vc);
        oacc[dt] = mfma32(pa[kst], vf, oacc[dt]);
      }
    }
    cur ^= 1;
  }
  // normalized bf16 partial O + (m,l) fp32
  unsigned short* Od = opart + ((size_t)(split*NH + h)*NTOK + nbq)*DH;
  #pragma unroll
  for (int r=0;r<16;r++){
    const int q = (r&3) + 8*(r>>2) + 4*hi;
    const float linv = 1.f / lacc[r];
    #pragma unroll
    for (int dt=0;dt<4;dt++)
      Od[(size_t)q*DH + dt*32 + la] = f2bf(oacc[dt][r] * linv);
  }
  if (la == 0){
    float* ml = mlbuf + ((size_t)(split*NH + h)*NTOK + nbq)*2;
    #pragma unroll
    for (int r=0;r<16;r++){
      const int q = (r&3) + 8*(r>>2) + 4*hi;
      ml[q*2]     = mk[r] * INV_KSC;
      ml[q*2 + 1] = lacc[r];
    }
  }
}

// ---------------- merge kv-splits -> ao_t (N,C) bf16 ----------------
__global__ __launch_bounds__(256) void k_merge(const unsigned short* __restrict__ opart,
                                               const float* __restrict__ mlbuf,
                                               unsigned short* __restrict__ ao_t){
  const int h = blockIdx.y;
  const int n = blockIdx.x*2 + (threadIdx.x >> 7);
  const int d = threadIdx.x & 127;
  float ms[NSPLIT], ls[NSPLIT], m = -1e30f;
  #pragma unroll
  for (int s=0;s<NSPLIT;s++){
    const float* ml = mlbuf + ((size_t)(s*NH + h)*NTOK + n)*2;
    ms[s] = ml[0]; ls[s] = ml[1];
    m = fmaxf(m, ms[s]);
  }
  float wsum = 0.f, o = 0.f;
  #pragma unroll
  for (int s=0;s<NSPLIT;s++){
    float wgt = exp2f((ms[s]-m)*KSC) * ls[s];
    wsum += wgt;
    o += wgt * bf2f(opart[((size_t)(s*NH + h)*NTOK + n)*DH + d]);
  }
  ao_t[(size_t)n*CDIM + h*DH + d] = f2bf(o / wsum);
}

extern "C" void kernel_launch(void* const* d_in, const int* in_sizes, int n_in,
                              void* d_out, int out_size, void* d_ws, size_t ws_size,
                              hipStream_t stream){
  const float* x      = (const float*)d_in[0];
  const float* norm_w = (const float*)d_in[1];
  const float* norm_b = (const float*)d_in[2];
  const float* qkv_w  = (const float*)d_in[3];
  const float* qkv_b  = (const float*)d_in[4];
  const float* proj_w = (const float*)d_in[5];
  const float* proj_b = (const float*)d_in[6];
  float* out = (float*)d_out;

  char* ws = (char*)d_ws;
  unsigned short* qw  = (unsigned short*)(ws);             // 1536x512 bf16
  unsigned short* pw  = (unsigned short*)(ws + 1572864);   // 512x512 bf16
  unsigned short* h_t = (unsigned short*)(ws + 2097152);   // 4096x512 bf16
  unsigned short* q_t = (unsigned short*)(ws + 6291456);   // 4x4096x128 bf16
  unsigned short* k_t = (unsigned short*)(ws + 10485760);  // 4x4096x128 bf16
  unsigned short* vb  = (unsigned short*)(ws + 14680064);  // 4x128x4096 bf16
  unsigned short* ao  = (unsigned short*)(ws + 18874368);  // 4096x512 bf16
  float* stats        = (float*)(ws + 23068672);           // 64 floats
  unsigned short* opart = (unsigned short*)(ws + 23072768);// 4x4x4096x128 bf16 = 16 MB
  float* mlbuf        = (float*)(ws + 39849984);           // 4x4x4096x2 f32 = 512 KB
  // end ≈ 40.4 MB of d_ws (matches previously-validated footprint)

  hipLaunchKernelGGL(k_convert, dim3(1024), dim3(256), 0, stream, qkv_w, proj_w, qw, pw);
  hipLaunchKernelGGL(k_gnstats, dim3(32), dim3(256), 0, stream, x, stats);
  hipLaunchKernelGGL(k_gnapply, dim3(64, 8), dim3(256), 0, stream, x, stats, norm_w, norm_b, h_t);
  hipLaunchKernelGGL((k_gemm<0>), dim3(32, 12), dim3(256), 0, stream,
                     qw, h_t, qkv_b, (const float*)nullptr,
                     q_t, k_t, vb, (float*)nullptr, 512);
  hipLaunchKernelGGL(k_attn, dim3(16*NSPLIT, NH), dim3(512), 0, stream, q_t, k_t, vb, opart, mlbuf);
  hipLaunchKernelGGL(k_merge, dim3(NTOK/2, NH), dim3(256), 0, stream, opart, mlbuf, ao);
  hipLaunchKernelGGL((k_gemm<1>), dim3(32, 4), dim3(256), 0, stream,
                     pw, ao, proj_b, x,
                     (unsigned short*)nullptr, (unsigned short*)nullptr, (unsigned short*)nullptr, out, 512);
}